// Round 3
// baseline (3322.263 us; speedup 1.0000x reference)
//
#include <hip/hip_runtime.h>
#include <math.h>

// Bidirectional 10-layer tanh RNN, T=512 B=64 H=100, + sigmoid head.
// Layers strictly sequential (bidir dependency). Per layer:
//   1) ingemm_kernel: z[dir][m][h] = In[m][:] . W[dir*100+h][:] + bias
//   2) scan_kernel:   128 blocks = 2 dirs x 64 batch independent chains
// Final: outproj_kernel (wave-per-row dot200 + sigmoid).
//
// R3: scan_kernel shuffle-free. R1/R2 showed the step is serial-LATENCY
// bound (LDS round trips), not LDS-pipe or VALU bound: __shfl_xor lowers to
// ds_swizzle/bpermute = extra LDS hops on the chain. New layout: 1 output
// per lane (100 active lanes, 2 waves), full weight row w[100] in registers,
// h read via 25 broadcast ds_read_b128 (cheap), 4 independent 25-deep FMA
// chains, ZERO shuffles, one ds_write_b32, lgkmcnt(0)+raw s_barrier (no
// vmcnt drain), 4-deep z prefetch ring.

#define T_LEN 512
#define BATCH 64
#define HID   100
#define M_TOT (T_LEN * BATCH)   // 32768

// ---------------- input GEMM ----------------
__global__ __launch_bounds__(256) void ingemm_kernel(
    const float* __restrict__ In, const float* __restrict__ W,
    const float* __restrict__ bih, const float* __restrict__ bhh,
    float* __restrict__ z, int K)
{
    __shared__ float As[16][68];
    __shared__ float Bs[16][68];
    const int tid = threadIdx.x;
    const int m0 = blockIdx.x * 64;
    const int n0 = blockIdx.y * 64;
    const int tx = tid & 15, ty = tid >> 4;
    const int lm = tid >> 2;          // 0..63
    const int lk = (tid & 3) << 2;    // 0,4,8,12

    float acc[4][4];
    #pragma unroll
    for (int i = 0; i < 4; ++i)
        #pragma unroll
        for (int j = 0; j < 4; ++j) acc[i][j] = 0.f;

    for (int k0 = 0; k0 < K; k0 += 16) {
        float4 av = make_float4(0.f,0.f,0.f,0.f);
        float4 bv = make_float4(0.f,0.f,0.f,0.f);
        if (k0 + lk < K)   // K%4==0 so a 4-chunk is fully in or out
            av = *(const float4*)(In + (size_t)(m0 + lm) * K + k0 + lk);
        const int nrow = n0 + lm;
        if (nrow < 200 && k0 + lk < K)
            bv = *(const float4*)(W + (size_t)nrow * K + k0 + lk);
        As[lk+0][lm]=av.x; As[lk+1][lm]=av.y; As[lk+2][lm]=av.z; As[lk+3][lm]=av.w;
        Bs[lk+0][lm]=bv.x; Bs[lk+1][lm]=bv.y; Bs[lk+2][lm]=bv.z; Bs[lk+3][lm]=bv.w;
        __syncthreads();
        #pragma unroll
        for (int kk = 0; kk < 16; ++kk) {
            float4 a4 = *(const float4*)&As[kk][ty << 2];
            float4 b4 = *(const float4*)&Bs[kk][tx << 2];
            float a[4] = {a4.x, a4.y, a4.z, a4.w};
            float b[4] = {b4.x, b4.y, b4.z, b4.w};
            #pragma unroll
            for (int i = 0; i < 4; ++i)
                #pragma unroll
                for (int j = 0; j < 4; ++j)
                    acc[i][j] += a[i] * b[j];
        }
        __syncthreads();
    }
    #pragma unroll
    for (int i = 0; i < 4; ++i) {
        const int m = m0 + (ty << 2) + i;
        #pragma unroll
        for (int j = 0; j < 4; ++j) {
            const int n = n0 + (tx << 2) + j;
            if (n < 200) {
                const int dir = (n >= 100) ? 1 : 0;
                const int h = n - dir * 100;
                z[(size_t)dir * M_TOT * HID + (size_t)m * HID + h] =
                    acc[i][j] + bih[n] + bhh[n];
            }
        }
    }
}

// ---------------- recurrent scan ----------------
// One block (128 threads, 2 waves) per (dir, batch) chain.
// Lane tid (< 100 active) owns output j = tid; full weight row in registers.
__global__ __launch_bounds__(128) void scan_kernel(
    const float* __restrict__ z,    // [2][M][HID]
    const float* __restrict__ Whh,  // [2][HID][HID] for this layer
    float* __restrict__ out)        // [M][200]
{
    const int dir = blockIdx.x >> 6;
    const int b   = blockIdx.x & 63;
    const int tid = threadIdx.x;        // 0..127
    const bool active = (tid < HID);
    const int j = active ? tid : (HID - 1);   // clamped for safe addressing

    __shared__ float h_lds[2][128];
    for (int i = tid; i < 256; i += 128) (&h_lds[0][0])[i] = 0.f;

    // full weight row j in registers (statically indexed, fully unrolled)
    float w[100];
    {
        const float* wr = Whh + ((size_t)dir * HID + j) * HID;
        #pragma unroll
        for (int q = 0; q < 25; ++q) {
            float4 v = *(const float4*)(wr + 4 * q);
            w[4*q+0] = v.x; w[4*q+1] = v.y;
            w[4*q+2] = v.z; w[4*q+3] = v.w;
        }
    }
    __syncthreads();   // h_lds zero-init visible

    const ptrdiff_t zstride = BATCH * HID;
    const ptrdiff_t ostride = BATCH * 200;
    const int t0 = dir ? (T_LEN - 1) : 0;
    const ptrdiff_t zstep = dir ? -zstride : zstride;
    const ptrdiff_t ostep = dir ? -ostride : ostride;
    const ptrdiff_t zstep2 = 2 * zstep, zstep3 = 3 * zstep, zstep4 = 4 * zstep;

    const float* zp = z + (size_t)dir * M_TOT * HID + (size_t)b * HID + j
                        + (ptrdiff_t)t0 * zstride;
    float*       op = out + (size_t)b * 200 + dir * HID + j
                        + (ptrdiff_t)t0 * ostride;

    // 4-deep z prefetch ring (statically indexed named regs)
    float zr0 = zp[0];
    float zr1 = zp[zstep];
    float zr2 = zp[zstep2];
    float zr3 = zp[zstep3];
    const float* zpf = zp + zstep4;

// One step: 25 broadcast b128 LDS reads (all lanes same addr), 100 FMAs in
// 4 independent 25-deep chains, combine, tanh, one ds_write_b32, out store.
// Raw barrier: only lgkmcnt drained (global loads/stores stay in flight).
// All 128 lanes write h (lanes 100..127 hit pad slots, never read).
#define RNN_STEP(ZREG, DO_PF, PFOFF, RD, WRB)                           \
  do {                                                                  \
    const float zin = ZREG;                                             \
    if (DO_PF) ZREG = *(zpf + (PFOFF));   /* fire-and-forget prefetch */\
    const float4* hp = (const float4*)(RD);                             \
    float acc0 = 0.f, acc1 = 0.f, acc2 = 0.f, acc3 = 0.f;               \
    _Pragma("unroll")                                                   \
    for (int q = 0; q < 25; ++q) {                                      \
      float4 hv = hp[q];                                                \
      acc0 += w[4*q+0] * hv.x;                                          \
      acc1 += w[4*q+1] * hv.y;                                          \
      acc2 += w[4*q+2] * hv.z;                                          \
      acc3 += w[4*q+3] * hv.w;                                          \
    }                                                                   \
    float tot = (acc0 + acc1) + (acc2 + acc3);                          \
    float xin = zin + tot;                                              \
    float ax = fabsf(xin);                                              \
    float e = __expf(2.f * ax);                                         \
    float r = 1.f - 2.f / (e + 1.f);                                    \
    float val = copysignf(r, xin);                                      \
    (WRB)[tid] = val;                                                   \
    if (active) *op = val;                                              \
    op += ostep;                                                        \
    asm volatile("s_waitcnt lgkmcnt(0)" ::: "memory");                  \
    __builtin_amdgcn_sched_barrier(0);                                  \
    __builtin_amdgcn_s_barrier();                                       \
    __builtin_amdgcn_sched_barrier(0);                                  \
  } while (0)

    float* const h0 = &h_lds[0][0];
    float* const h1 = &h_lds[1][0];

    // main: 127 groups of 4 steps, prefetching steps s+4..s+7
    for (int g = 0; g < (T_LEN / 4) - 1; ++g) {
        RNN_STEP(zr0, 1, 0,      h0, h1);
        RNN_STEP(zr1, 1, zstep,  h1, h0);
        RNN_STEP(zr2, 1, zstep2, h0, h1);
        RNN_STEP(zr3, 1, zstep3, h1, h0);
        zpf += zstep4;
    }
    // tail: last 4 steps, no prefetch
    RNN_STEP(zr0, 0, 0, h0, h1);
    RNN_STEP(zr1, 0, 0, h1, h0);
    RNN_STEP(zr2, 0, 0, h0, h1);
    RNN_STEP(zr3, 0, 0, h1, h0);

#undef RNN_STEP
}

// ---------------- output projection ----------------
__global__ __launch_bounds__(256) void outproj_kernel(
    const float* __restrict__ h, const float* __restrict__ Wout,
    const float* __restrict__ bout, float* __restrict__ y)
{
    const int gid = blockIdx.x * 256 + threadIdx.x;
    const int wid = gid >> 6;
    const int lane = threadIdx.x & 63;
    if (wid >= M_TOT) return;
    const float* row = h + (size_t)wid * 200;
    float acc = 0.f;
    for (int k = lane; k < 200; k += 64) acc += row[k] * Wout[k];
    #pragma unroll
    for (int off = 32; off > 0; off >>= 1) acc += __shfl_xor(acc, off);
    if (lane == 0) y[wid] = 1.f / (1.f + __expf(-(acc + bout[0])));
}

extern "C" void kernel_launch(void* const* d_in, const int* in_sizes, int n_in,
                              void* d_out, int out_size, void* d_ws, size_t ws_size,
                              hipStream_t stream)
{
    const float* x     = (const float*)d_in[0];
    const float* W_ih0 = (const float*)d_in[1];
    const float* W_ih  = (const float*)d_in[2];
    const float* W_hh  = (const float*)d_in[3];
    const float* b_ih  = (const float*)d_in[4];
    const float* b_hh  = (const float*)d_in[5];
    const float* W_out = (const float*)d_in[6];
    const float* b_out = (const float*)d_in[7];
    float* y = (float*)d_out;

    float* z    = (float*)d_ws;                          // 2*M*100 floats
    float* buf0 = z + (size_t)2 * M_TOT * HID;           // M*200
    float* buf1 = buf0 + (size_t)M_TOT * 200;            // M*200

    for (int l = 0; l < 10; ++l) {
        const float* In = (l == 0) ? x : ((l & 1) ? buf0 : buf1);
        float* Out      = (l & 1) ? buf1 : buf0;
        const int K     = (l == 0) ? 100 : 200;
        const float* W  = (l == 0) ? W_ih0 : (W_ih + (size_t)(l - 1) * 2 * 100 * 200);
        ingemm_kernel<<<dim3(M_TOT / 64, 4), 256, 0, stream>>>(
            In, W, b_ih + l * 200, b_hh + l * 200, z, K);
        scan_kernel<<<128, 128, 0, stream>>>(
            z, W_hh + (size_t)l * 2 * HID * HID, Out);
    }
    outproj_kernel<<<M_TOT / 4, 256, 0, stream>>>(buf1, W_out, b_out, y);
}

// Round 4
// 2200.938 us; speedup vs baseline: 1.5095x; 1.5095x over previous
//
#include <hip/hip_runtime.h>
#include <math.h>

// Bidirectional 10-layer tanh RNN, T=512 B=64 H=100, + sigmoid head.
// Layers strictly sequential (bidir dependency). Per layer:
//   1) ingemm_kernel: z[dir][m][h] = In[m][:] . W[dir*100+h][:] + bias
//   2) scan_kernel:   128 blocks = 2 dirs x 64 batch independent chains
// Final: outproj_kernel (wave-per-row dot200 + sigmoid).
//
// R4: scan empirics (R1 4-wave 1030cy < R2/R3 2-wave 1130/1337cy) show
// intra-block wave overlap is the latency hider; DS instr count is the
// remaining big term. Layout: 256 thr, j spread over ALL 4 waves
// (jj = wave + 4*(lane>>2), rows {2jj,2jj+1}), k split 4 ways (ks=lane&3,
// 28-float padded slices). 7 ds_read_b128/wave (28 total, was 52),
// reduction via 2 guaranteed-DPP quad-perm hops (update_dpp 0xB1/0x4E,
// VALU-speed, no LDS), 1 ds_write_b32/wave. Raw s_barrier + lgkmcnt-only
// drain + 4-deep z prefetch ring kept from R1.

#define T_LEN 512
#define BATCH 64
#define HID   100
#define M_TOT (T_LEN * BATCH)   // 32768

// ---------------- input GEMM ----------------
__global__ __launch_bounds__(256) void ingemm_kernel(
    const float* __restrict__ In, const float* __restrict__ W,
    const float* __restrict__ bih, const float* __restrict__ bhh,
    float* __restrict__ z, int K)
{
    __shared__ float As[16][68];
    __shared__ float Bs[16][68];
    const int tid = threadIdx.x;
    const int m0 = blockIdx.x * 64;
    const int n0 = blockIdx.y * 64;
    const int tx = tid & 15, ty = tid >> 4;
    const int lm = tid >> 2;          // 0..63
    const int lk = (tid & 3) << 2;    // 0,4,8,12

    float acc[4][4];
    #pragma unroll
    for (int i = 0; i < 4; ++i)
        #pragma unroll
        for (int j = 0; j < 4; ++j) acc[i][j] = 0.f;

    for (int k0 = 0; k0 < K; k0 += 16) {
        float4 av = make_float4(0.f,0.f,0.f,0.f);
        float4 bv = make_float4(0.f,0.f,0.f,0.f);
        if (k0 + lk < K)   // K%4==0 so a 4-chunk is fully in or out
            av = *(const float4*)(In + (size_t)(m0 + lm) * K + k0 + lk);
        const int nrow = n0 + lm;
        if (nrow < 200 && k0 + lk < K)
            bv = *(const float4*)(W + (size_t)nrow * K + k0 + lk);
        As[lk+0][lm]=av.x; As[lk+1][lm]=av.y; As[lk+2][lm]=av.z; As[lk+3][lm]=av.w;
        Bs[lk+0][lm]=bv.x; Bs[lk+1][lm]=bv.y; Bs[lk+2][lm]=bv.z; Bs[lk+3][lm]=bv.w;
        __syncthreads();
        #pragma unroll
        for (int kk = 0; kk < 16; ++kk) {
            float4 a4 = *(const float4*)&As[kk][ty << 2];
            float4 b4 = *(const float4*)&Bs[kk][tx << 2];
            float a[4] = {a4.x, a4.y, a4.z, a4.w};
            float b[4] = {b4.x, b4.y, b4.z, b4.w};
            #pragma unroll
            for (int i = 0; i < 4; ++i)
                #pragma unroll
                for (int j = 0; j < 4; ++j)
                    acc[i][j] += a[i] * b[j];
        }
        __syncthreads();
    }
    #pragma unroll
    for (int i = 0; i < 4; ++i) {
        const int m = m0 + (ty << 2) + i;
        #pragma unroll
        for (int j = 0; j < 4; ++j) {
            const int n = n0 + (tx << 2) + j;
            if (n < 200) {
                const int dir = (n >= 100) ? 1 : 0;
                const int h = n - dir * 100;
                z[(size_t)dir * M_TOT * HID + (size_t)m * HID + h] =
                    acc[i][j] + bih[n] + bhh[n];
            }
        }
    }
}

// DPP quad-perm xor helpers — guaranteed VALU lane exchange (no LDS).
// quad_perm ctrl = p0 | p1<<2 | p2<<4 | p3<<6.
// xor1: {1,0,3,2} = 0xB1 ; xor2: {2,3,0,1} = 0x4E.
__device__ __forceinline__ float dpp_qxor1(float x) {
    int i = __float_as_int(x);
    i = __builtin_amdgcn_update_dpp(0, i, 0xB1, 0xF, 0xF, false);
    return __int_as_float(i);
}
__device__ __forceinline__ float dpp_qxor2(float x) {
    int i = __float_as_int(x);
    i = __builtin_amdgcn_update_dpp(0, i, 0x4E, 0xF, 0xF, false);
    return __int_as_float(i);
}

// ---------------- recurrent scan ----------------
// One block (256 threads, 4 waves) per (dir, batch) chain.
// Lane (wave w, lane l): ks = l&3 (k-slice), jj = w + 4*(l>>2) (row pair).
// Active jj < 50; quads are jj-uniform so DPP quads never mix active/inactive.
__global__ __launch_bounds__(256) void scan_kernel(
    const float* __restrict__ z,    // [2][M][HID]
    const float* __restrict__ Whh,  // [2][HID][HID] for this layer
    float* __restrict__ out)        // [M][200]
{
    const int dir = blockIdx.x >> 6;
    const int b   = blockIdx.x & 63;
    const int tid = threadIdx.x;        // 0..255
    const int w   = tid >> 6;           // wave 0..3
    const int lane= tid & 63;
    const int ks  = lane & 3;           // k-slice 0..3
    const int jslot = lane >> 2;        // 0..15
    const int jj  = w + 4 * jslot;      // 0..63, spread across waves
    const bool active = (jj < 50);
    const int jjc = active ? jj : 49;   // clamped for safe addressing
    const int kb  = 28 * ks;            // k-slice base (h padded to 128)
    const int jout = 2 * jjc + (ks & 1);        // row this lane finalizes
    const bool writer = active && (ks < 2);     // ks 0,1 write rows 2jj,2jj+1

    __shared__ float h_lds[2][128];
    for (int i = tid; i < 256; i += 256) (&h_lds[0][0])[i] = 0.f;

    // per-lane weights: w2[r][kk] = Whh[dir][2*jj+r][kb+kk], zero for k>=100
    float w2[2][28];
    #pragma unroll
    for (int r = 0; r < 2; ++r) {
        const float* wr = Whh + ((size_t)dir * HID + 2 * jjc + r) * HID + kb;
        #pragma unroll
        for (int q = 0; q < 7; ++q) {
            float4 v = make_float4(0.f, 0.f, 0.f, 0.f);
            if (kb + 4 * q + 3 < HID)   // ks<3: 7 valid; ks==3: 4 valid (k=84..99)
                v = *(const float4*)(wr + 4 * q);
            w2[r][4*q+0] = v.x; w2[r][4*q+1] = v.y;
            w2[r][4*q+2] = v.z; w2[r][4*q+3] = v.w;
        }
    }
    __syncthreads();   // h_lds zero-init visible

    const ptrdiff_t zstride = BATCH * HID;
    const ptrdiff_t ostride = BATCH * 200;
    const int t0 = dir ? (T_LEN - 1) : 0;
    const ptrdiff_t zstep = dir ? -zstride : zstride;
    const ptrdiff_t ostep = dir ? -ostride : ostride;
    const ptrdiff_t zstep2 = 2 * zstep, zstep3 = 3 * zstep, zstep4 = 4 * zstep;

    const float* zp = z + (size_t)dir * M_TOT * HID + (size_t)b * HID + jout
                        + (ptrdiff_t)t0 * zstride;
    float*       op = out + (size_t)b * 200 + dir * HID + jout
                        + (ptrdiff_t)t0 * ostride;

    // 4-deep z prefetch ring (statically indexed named regs)
    float zr0 = zp[0];
    float zr1 = zp[zstep];
    float zr2 = zp[zstep2];
    float zr3 = zp[zstep3];
    const float* zpf = zp + zstep4;

// One step: 7 b128 LDS reads/wave (4 distinct bank-disjoint slices per
// instr, broadcast x16), 56 FMAs vs register weights (two 28-deep chains),
// 2-hop DPP transpose-reduce (lane ks ends with row 2jj+(ks&1) total),
// tanh, ds_write_b32 from ks<2, out store. Raw barrier: lgkmcnt only.
#define RNN_STEP(ZREG, DO_PF, PFOFF, RD, WRB)                           \
  do {                                                                  \
    const float zin = ZREG;                                             \
    if (DO_PF) ZREG = *(zpf + (PFOFF));   /* fire-and-forget prefetch */\
    const float4* hp = (const float4*)((RD) + kb);                      \
    float a0 = 0.f, a1 = 0.f;                                           \
    _Pragma("unroll")                                                   \
    for (int q = 0; q < 7; ++q) {                                       \
      float4 hv = hp[q];                                                \
      a0 += w2[0][4*q+0] * hv.x; a0 += w2[0][4*q+1] * hv.y;             \
      a0 += w2[0][4*q+2] * hv.z; a0 += w2[0][4*q+3] * hv.w;             \
      a1 += w2[1][4*q+0] * hv.x; a1 += w2[1][4*q+1] * hv.y;             \
      a1 += w2[1][4*q+2] * hv.z; a1 += w2[1][4*q+3] * hv.w;             \
    }                                                                   \
    /* hop1 (xor1): lane keeps row (ks&1), receives partner's */        \
    float keep = (ks & 1) ? a1 : a0;                                    \
    float send = (ks & 1) ? a0 : a1;                                    \
    float s = keep + dpp_qxor1(send);                                   \
    /* hop2 (xor2): sum the two slice-pairs -> full 100-k total */      \
    float tot = s + dpp_qxor2(s);                                       \
    float xin = zin + tot;                                              \
    float ax = fabsf(xin);                                              \
    float e = __expf(2.f * ax);                                         \
    float r = 1.f - 2.f / (e + 1.f);                                    \
    float val = copysignf(r, xin);                                      \
    if (writer) {                                                       \
      (WRB)[jout] = val;                                                \
      *op = val;                                                        \
    }                                                                   \
    op += ostep;                                                        \
    asm volatile("s_waitcnt lgkmcnt(0)" ::: "memory");                  \
    __builtin_amdgcn_sched_barrier(0);                                  \
    __builtin_amdgcn_s_barrier();                                       \
    __builtin_amdgcn_sched_barrier(0);                                  \
  } while (0)

    float* const h0 = &h_lds[0][0];
    float* const h1 = &h_lds[1][0];

    // main: 127 groups of 4 steps, prefetching steps s+4..s+7
    for (int g = 0; g < (T_LEN / 4) - 1; ++g) {
        RNN_STEP(zr0, 1, 0,      h0, h1);
        RNN_STEP(zr1, 1, zstep,  h1, h0);
        RNN_STEP(zr2, 1, zstep2, h0, h1);
        RNN_STEP(zr3, 1, zstep3, h1, h0);
        zpf += zstep4;
    }
    // tail: last 4 steps, no prefetch
    RNN_STEP(zr0, 0, 0, h0, h1);
    RNN_STEP(zr1, 0, 0, h1, h0);
    RNN_STEP(zr2, 0, 0, h0, h1);
    RNN_STEP(zr3, 0, 0, h1, h0);

#undef RNN_STEP
}

// ---------------- output projection ----------------
__global__ __launch_bounds__(256) void outproj_kernel(
    const float* __restrict__ h, const float* __restrict__ Wout,
    const float* __restrict__ bout, float* __restrict__ y)
{
    const int gid = blockIdx.x * 256 + threadIdx.x;
    const int wid = gid >> 6;
    const int lane = threadIdx.x & 63;
    if (wid >= M_TOT) return;
    const float* row = h + (size_t)wid * 200;
    float acc = 0.f;
    for (int k = lane; k < 200; k += 64) acc += row[k] * Wout[k];
    #pragma unroll
    for (int off = 32; off > 0; off >>= 1) acc += __shfl_xor(acc, off);
    if (lane == 0) y[wid] = 1.f / (1.f + __expf(-(acc + bout[0])));
}

extern "C" void kernel_launch(void* const* d_in, const int* in_sizes, int n_in,
                              void* d_out, int out_size, void* d_ws, size_t ws_size,
                              hipStream_t stream)
{
    const float* x     = (const float*)d_in[0];
    const float* W_ih0 = (const float*)d_in[1];
    const float* W_ih  = (const float*)d_in[2];
    const float* W_hh  = (const float*)d_in[3];
    const float* b_ih  = (const float*)d_in[4];
    const float* b_hh  = (const float*)d_in[5];
    const float* W_out = (const float*)d_in[6];
    const float* b_out = (const float*)d_in[7];
    float* y = (float*)d_out;

    float* z    = (float*)d_ws;                          // 2*M*100 floats
    float* buf0 = z + (size_t)2 * M_TOT * HID;           // M*200
    float* buf1 = buf0 + (size_t)M_TOT * 200;            // M*200

    for (int l = 0; l < 10; ++l) {
        const float* In = (l == 0) ? x : ((l & 1) ? buf0 : buf1);
        float* Out      = (l & 1) ? buf1 : buf0;
        const int K     = (l == 0) ? 100 : 200;
        const float* W  = (l == 0) ? W_ih0 : (W_ih + (size_t)(l - 1) * 2 * 100 * 200);
        ingemm_kernel<<<dim3(M_TOT / 64, 4), 256, 0, stream>>>(
            In, W, b_ih + l * 200, b_hh + l * 200, z, K);
        scan_kernel<<<128, 256, 0, stream>>>(
            z, W_hh + (size_t)l * 2 * HID * HID, Out);
    }
    outproj_kernel<<<M_TOT / 4, 256, 0, stream>>>(buf1, W_out, b_out, y);
}